// Round 6
// baseline (377.325 us; speedup 1.0000x reference)
//
#include <hip/hip_runtime.h>
#include <hip/hip_bf16.h>

typedef _Float16 f16x8 __attribute__((ext_vector_type(8)));
typedef _Float16 f16x4 __attribute__((ext_vector_type(4)));
typedef float f32x4 __attribute__((ext_vector_type(4)));
typedef int i32x4 __attribute__((ext_vector_type(4)));

__device__ __forceinline__ float bf2f(unsigned short u) {
  union { unsigned int i; float f; } x; x.i = ((unsigned int)u) << 16; return x.f;
}
__device__ __forceinline__ _Float16 h16(float f) {
  return (_Float16)fminf(fmaxf(f, -60000.f), 60000.f);
}
__device__ __forceinline__ float neglog(float u) {
  if (u > 0.99f) {
    const float d = 1.0f - u;
    return d + 0.5f * d * d + (1.0f / 3.0f) * d * d * d;
  }
  return -__logf(u);
}
__device__ __forceinline__ float wsum(float v) {
#pragma unroll
  for (int off = 1; off < 64; off <<= 1) v += __shfl_xor(v, off, 64);
  return v;
}
__device__ __forceinline__ f16x8 cvt8_bf(const unsigned short* p) {
  union { i32x4 v; unsigned short u[8]; } ld;
  ld.v = *(const i32x4*)p;
  f16x8 r;
#pragma unroll
  for (int j = 0; j < 8; j++) r[j] = h16(bf2f(ld.u[j]));
  return r;
}
__device__ __forceinline__ f16x8 cvt8_f32(const float* p) {
  f32x4 a = *(const f32x4*)p;
  f32x4 b = *(const f32x4*)(p + 4);
  f16x8 r;
#pragma unroll
  for (int j = 0; j < 4; j++) { r[j] = h16(a[j]); r[4 + j] = h16(b[j]); }
  return r;
}
// dtype of float inputs: 0 = bf16, 1 = fp32. Per-wave inline (uniform result).
__device__ __forceinline__ int detect_flg(const unsigned short* __restrict__ g) {
  const float f = bf2f(g[(threadIdx.x & 63) * 2]);
  const unsigned long long m = __ballot((f >= 8e-7f) && (f <= 1.0f));
  return (m == ~0ull) ? 0 : 1;
}

// ---------------------------------------------------------------------------
// Kernel 0b: convert hidden + Wq/Wk/Wv to fp16 once.
// dst: [hid 2M | Wq 1M | Wk 1M | Wv 1M] halves.
// ---------------------------------------------------------------------------
__global__ __launch_bounds__(256) void cvt_inputs(
    const void* __restrict__ h, const void* __restrict__ wq,
    const void* __restrict__ wk, const void* __restrict__ wv,
    const unsigned short* __restrict__ gum, _Float16* __restrict__ dst)
{
  const int flg = detect_flg(gum);
  const int y = blockIdx.y;
  const int n = (y == 0) ? (2 * 1024 * 1024) : (1024 * 1024);
  const int idx = (blockIdx.x * 256 + threadIdx.x) * 4;
  if (idx >= n) return;
  const void* src = (y == 0) ? h : (y == 1) ? wq : (y == 2) ? wk : wv;
  const size_t base = (y == 0) ? 0 : (size_t)(2 * 1024 * 1024) + (size_t)(y - 1) * 1024 * 1024;
  f16x4 o;
  if (flg) {
    f32x4 v = *(const f32x4*)((const float*)src + idx);
#pragma unroll
    for (int j = 0; j < 4; j++) o[j] = h16(v[j]);
  } else {
    union { unsigned long long q; unsigned short u[4]; } ld;
    ld.q = *(const unsigned long long*)((const unsigned short*)src + idx);
#pragma unroll
    for (int j = 0; j < 4; j++) o[j] = h16(bf2f(ld.u[j]));
  }
  *(f16x4*)(dst + base + idx) = o;
}

// ---------------------------------------------------------------------------
// Kernel 1: QKV projection, fp16 NT gemm 2048 x 3072 x 1024.
// 64x64 tiles, BK=64 -> 1536 blocks (6/CU); register-prefetched staging.
// ---------------------------------------------------------------------------
__global__ __launch_bounds__(256) void qkv_gemm(
    const _Float16* __restrict__ cvt,   // [hid | Wq | Wk | Wv]
    const unsigned short* __restrict__ bq, const unsigned short* __restrict__ bk,
    const unsigned short* __restrict__ bv,
    const unsigned short* __restrict__ gum,
    _Float16* __restrict__ q_ws, _Float16* __restrict__ k_ws,
    _Float16* __restrict__ v_ws)
{
  __shared__ _Float16 At[64][72];
  __shared__ _Float16 Bt[64][72];
  const int flg = detect_flg(gum);
  const int tn = blockIdx.x;        // 32 M-tiles of 64 rows
  const int to = blockIdx.y;        // 48 N-tiles of 64 cols over [q|k|v]
  const int mat = to >> 4;          // 0=q 1=k 2=v
  const int o0 = (to & 15) * 64;
  const _Float16* hid16 = cvt;
  const _Float16* W16 = cvt + (size_t)(2 * 1024 * 1024) + (size_t)mat * 1024 * 1024;
  const unsigned short* bias = (mat == 0) ? bq : (mat == 1) ? bk : bv;
  const float* biasf = (const float*)bias;
  const int tid = threadIdx.x;
  const int lane = tid & 63, wave = tid >> 6;
  const int wm = (wave >> 1) * 32, wn = (wave & 1) * 32;  // 2x2 quadrants 32x32
  const int lm = lane & 15, lq = lane >> 4;
  f32x4 acc[2][2] = {};

  // staging coords: 64 rows x 8 chunks of 16B, 2 rounds of 256 threads
  const int r0s = tid >> 3, c8 = tid & 7;
  i32x4 ra[2], rb[2];
#pragma unroll
  for (int i = 0; i < 2; i++) {
    const int r = r0s + i * 32;
    ra[i] = *(const i32x4*)(hid16 + (size_t)(tn * 64 + r) * 1024 + 0 + c8 * 8);
    rb[i] = *(const i32x4*)(W16 + (size_t)(o0 + r) * 1024 + 0 + c8 * 8);
  }

  for (int kc = 0; kc < 1024; kc += 64) {
    __syncthreads();
#pragma unroll
    for (int i = 0; i < 2; i++) {
      const int r = r0s + i * 32;
      *(i32x4*)(&At[r][c8 * 8]) = ra[i];
      *(i32x4*)(&Bt[r][c8 * 8]) = rb[i];
    }
    __syncthreads();
    if (kc < 960) {
#pragma unroll
      for (int i = 0; i < 2; i++) {
        const int r = r0s + i * 32;
        ra[i] = *(const i32x4*)(hid16 + (size_t)(tn * 64 + r) * 1024 + kc + 64 + c8 * 8);
        rb[i] = *(const i32x4*)(W16 + (size_t)(o0 + r) * 1024 + kc + 64 + c8 * 8);
      }
    }
    f16x8 af[2][2], bfr[2][2];
#pragma unroll
    for (int mt = 0; mt < 2; mt++)
#pragma unroll
      for (int k2 = 0; k2 < 2; k2++)
        af[mt][k2] = *(const f16x8*)(&At[wm + mt * 16 + lm][k2 * 32 + lq * 8]);
#pragma unroll
    for (int nt = 0; nt < 2; nt++)
#pragma unroll
      for (int k2 = 0; k2 < 2; k2++)
        bfr[nt][k2] = *(const f16x8*)(&Bt[wn + nt * 16 + lm][k2 * 32 + lq * 8]);
#pragma unroll
    for (int mt = 0; mt < 2; mt++)
#pragma unroll
      for (int nt = 0; nt < 2; nt++)
#pragma unroll
        for (int k2 = 0; k2 < 2; k2++)
          acc[mt][nt] = __builtin_amdgcn_mfma_f32_16x16x32_f16(
              af[mt][k2], bfr[nt][k2], acc[mt][nt], 0, 0, 0);
  }

  _Float16* dst = (mat == 0) ? q_ws : (mat == 1) ? k_ws : v_ws;
#pragma unroll
  for (int nt = 0; nt < 2; nt++) {
    const int ol = o0 + wn + nt * 16 + lm;
    const float bias_v = flg ? biasf[ol] : bf2f(bias[ol]);
    const int hh = ol >> 6, dd = ol & 63;
#pragma unroll
    for (int mt = 0; mt < 2; mt++) {
#pragma unroll
      for (int rg = 0; rg < 4; rg++) {
        const int n = tn * 64 + wm + mt * 16 + lq * 4 + rg;  // b*1024+s
        const int b = n >> 10, s = n & 1023;
        dst[((size_t)(b * 16 + hh) * 1024 + s) * 64 + dd] = h16(acc[mt][nt][rg] + bias_v);
      }
    }
  }
}

// ---------------------------------------------------------------------------
// Kernel 1b: transpose v [bh][s][64] -> vT [bh][64][s] via LDS 64x64 tiles.
// ---------------------------------------------------------------------------
__global__ __launch_bounds__(256) void transpose_v(
    const _Float16* __restrict__ v_ws, _Float16* __restrict__ vT_ws)
{
  __shared__ unsigned short Tt[64 * 66];
  const int st = blockIdx.x;   // 16 s-tiles
  const int bh = blockIdx.y;   // 32
  const int tid = threadIdx.x;
  const unsigned short* src = (const unsigned short*)(v_ws + (size_t)bh * 65536);
#pragma unroll
  for (int i = 0; i < 2; i++) {
    const int cid = i * 256 + tid;
    const int r = cid >> 3, c8 = cid & 7;
    union { i32x4 v; unsigned int w[4]; } ld;
    ld.v = *(const i32x4*)(src + (size_t)(st * 64 + r) * 64 + c8 * 8);
#pragma unroll
    for (int w = 0; w < 4; w++)
      *(unsigned int*)(&Tt[r * 66 + c8 * 8 + w * 2]) = ld.w[w];
  }
  __syncthreads();
  const int d = tid >> 2, sc = (tid & 3) * 16;
  unsigned short us[16];
#pragma unroll
  for (int j = 0; j < 16; j++) us[j] = Tt[(sc + j) * 66 + d];
  unsigned short* dst = (unsigned short*)(vT_ws + (size_t)bh * 65536 + (size_t)d * 1024 + st * 64 + sc);
#pragma unroll
  for (int w = 0; w < 4; w++)
    *(unsigned long long*)(dst + w * 4) = *(unsigned long long*)(us + w * 4);
}

// ---------------------------------------------------------------------------
// Kernel 2: fused scores + rel-pos + gumbel double-softmax + PV.
// One block (4 waves) per (b, h, 16-row l-tile). 2048 blocks, 4 blocks/CU.
// Latency-pipelined: phase A prefetches K/E one chunk ahead (1 barrier/chunk,
// double-buffered Ub); phase B prefetches next row's gumbel+scores; phase C
// uses 4 independent accumulators.
// ---------------------------------------------------------------------------
#define ROWH 1048

__global__ __launch_bounds__(256, 4) void attn_kernel(
    const _Float16* __restrict__ q_ws, const _Float16* __restrict__ k_ws,
    const _Float16* __restrict__ vT_ws,
    const unsigned short* __restrict__ dist_emb,
    const unsigned short* __restrict__ gumbel_u,
    const unsigned short* __restrict__ mask,
    float* __restrict__ out)
{
  __shared__ _Float16 St[16 * ROWH];        // scores -> probs in place (fp16)
  __shared__ _Float16 Ub[2][16][96];        // rel-pos band, double-buffered
  const int flg = detect_flg(gumbel_u);
  const int blk = blockIdx.x;
  const int lt = blk & 63;
  const int bh = blk >> 6;
  const int b = bh >> 4, h = bh & 15;
  const int L = lt * 16;
  const _Float16* qp = q_ws + (size_t)bh * 65536;
  const _Float16* kp = k_ws + (size_t)bh * 65536;
  const _Float16* vp = vT_ws + (size_t)bh * 65536;
  const unsigned short* up = gumbel_u + (size_t)bh * 1024 * 1024;
  const float* upf = (const float*)gumbel_u + (size_t)bh * 1024 * 1024;
  const float* def = (const float*)dist_emb;
  const float* maskf = (const float*)mask;
  const int tid = threadIdx.x, wave = tid >> 6, lane = tid & 63;
  const int lm = lane & 15, lq = lane >> 4;
  const int rr = wave * 16 + lm;

  // Q tile A-fragments
  const f16x8 qa0 = *(const f16x8*)(qp + (L + lm) * 64 + lq * 8);
  const f16x8 qa1 = *(const f16x8*)(qp + (L + lm) * 64 + 32 + lq * 8);

  // hoisted mask values (one per chunk)
  float mv[16];
#pragma unroll
  for (int c = 0; c < 16; c++)
    mv[c] = flg ? maskf[b * 1024 + c * 64 + rr] : bf2f(mask[b * 1024 + c * 64 + rr]);

  // ---- Phase A ----
  // prefetch chunk 0: K rows and main E tile (t = wave)
  f16x8 kb0 = *(const f16x8*)(kp + (0 + rr) * 64 + lq * 8);
  f16x8 kb1 = *(const f16x8*)(kp + (0 + rr) * 64 + 32 + lq * 8);
  int jpre = (L + 960) + wave * 16 + lm;   // c0(R=0) + t*16 + lm, t=wave (<2047)
  f16x8 eb0 = flg ? cvt8_f32(def + (size_t)jpre * 64 + lq * 8)
                  : cvt8_bf(dist_emb + (size_t)jpre * 64 + lq * 8);
  f16x8 eb1 = flg ? cvt8_f32(def + (size_t)jpre * 64 + 32 + lq * 8)
                  : cvt8_bf(dist_emb + (size_t)jpre * 64 + 32 + lq * 8);

  int buf = 0;
  for (int R = 0; R < 1024; R += 64) {
    const int c0 = L - R + 960;
    // QK for this chunk (prefetched K)
    f32x4 aqk = {0.f, 0.f, 0.f, 0.f};
    aqk = __builtin_amdgcn_mfma_f32_16x16x32_f16(qa0, kb0, aqk, 0, 0, 0);
    aqk = __builtin_amdgcn_mfma_f32_16x16x32_f16(qa1, kb1, aqk, 0, 0, 0);
    // main rel-pos tile t = wave (prefetched E)
    {
      f32x4 au = {0.f, 0.f, 0.f, 0.f};
      au = __builtin_amdgcn_mfma_f32_16x16x32_f16(qa0, eb0, au, 0, 0, 0);
      au = __builtin_amdgcn_mfma_f32_16x16x32_f16(qa1, eb1, au, 0, 0, 0);
#pragma unroll
      for (int rg = 0; rg < 4; rg++)
        Ub[buf][lq * 4 + rg][wave * 16 + lm] = (_Float16)au[rg];
    }
    // 5th tile (t=4), rotating owner wave
    if (wave == ((R >> 6) & 3)) {
      int j = c0 + 64 + lm;
      if (j > 2046) j = 2046;   // band col 79 never gathered
      f16x8 xb0 = flg ? cvt8_f32(def + (size_t)j * 64 + lq * 8)
                      : cvt8_bf(dist_emb + (size_t)j * 64 + lq * 8);
      f16x8 xb1 = flg ? cvt8_f32(def + (size_t)j * 64 + 32 + lq * 8)
                      : cvt8_bf(dist_emb + (size_t)j * 64 + 32 + lq * 8);
      f32x4 au = {0.f, 0.f, 0.f, 0.f};
      au = __builtin_amdgcn_mfma_f32_16x16x32_f16(qa0, xb0, au, 0, 0, 0);
      au = __builtin_amdgcn_mfma_f32_16x16x32_f16(qa1, xb1, au, 0, 0, 0);
#pragma unroll
      for (int rg = 0; rg < 4; rg++)
        Ub[buf][lq * 4 + rg][64 + lm] = (_Float16)au[rg];
    }
    // prefetch next chunk's K + main E tile
    if (R < 960) {
      kb0 = *(const f16x8*)(kp + (R + 64 + rr) * 64 + lq * 8);
      kb1 = *(const f16x8*)(kp + (R + 64 + rr) * 64 + 32 + lq * 8);
      const int jn = (c0 - 64) + wave * 16 + lm;
      eb0 = flg ? cvt8_f32(def + (size_t)jn * 64 + lq * 8)
                : cvt8_bf(dist_emb + (size_t)jn * 64 + lq * 8);
      eb1 = flg ? cvt8_f32(def + (size_t)jn * 64 + 32 + lq * 8)
                : cvt8_bf(dist_emb + (size_t)jn * 64 + 32 + lq * 8);
    }
    __syncthreads();   // Ub[buf] complete
#pragma unroll
    for (int rg = 0; rg < 4; rg++) {
      const int i = lq * 4 + rg;
      St[i * ROWH + R + rr] =
          h16((aqk[rg] + (float)Ub[buf][i][i + 63 - rr]) * 0.125f + mv[R >> 6]);
    }
    buf ^= 1;
    // no second barrier: next chunk writes Ub[buf^1], readers use Ub[buf]
  }
  __syncthreads();   // all scores written (last chunk's St writes by all waves)

  // ---- Phase B: max-free double softmax, row-pipelined ----
  const int i0 = wave * 4;
  if (flg) {
    f32x4 nu[4]; f16x4 nsh[4];
#pragma unroll
    for (int c = 0; c < 4; c++) {
      nu[c] = *(const f32x4*)(upf + (size_t)(L + i0) * 1024 + c * 256 + lane * 4);
      nsh[c] = *(const f16x4*)(&St[i0 * ROWH + c * 256 + lane * 4]);
    }
#pragma unroll 1
    for (int k = 0; k < 4; k++) {
      const int i = i0 + k;
      f32x4 uv[4]; f16x4 sh[4];
#pragma unroll
      for (int c = 0; c < 4; c++) { uv[c] = nu[c]; sh[c] = nsh[c]; }
      if (k < 3) {
#pragma unroll
        for (int c = 0; c < 4; c++) {
          nu[c] = *(const f32x4*)(upf + (size_t)(L + i + 1) * 1024 + c * 256 + lane * 4);
          nsh[c] = *(const f16x4*)(&St[(i + 1) * ROWH + c * 256 + lane * 4]);
        }
      }
      float num1[16]; float s1 = 0.f;
#pragma unroll
      for (int c = 0; c < 4; c++)
#pragma unroll
        for (int j = 0; j < 4; j++) {
          const float nl = neglog(uv[c][j] + 1e-10f) + 1e-10f;
          num1[c * 4 + j] = __expf((float)sh[c][j]) * __builtin_amdgcn_rcpf(nl);
          s1 += num1[c * 4 + j];
        }
      s1 = wsum(s1);
      const float is1 = __builtin_amdgcn_rcpf(s1);
      float num2[16]; float s2 = 0.f;
#pragma unroll
      for (int c = 0; c < 4; c++)
#pragma unroll
        for (int j = 0; j < 4; j++) {
          num2[c * 4 + j] = __expf((float)sh[c][j] + num1[c * 4 + j] * is1);
          s2 += num2[c * 4 + j];
        }
      s2 = wsum(s2);
      const float is2 = __builtin_amdgcn_rcpf(s2);
#pragma unroll
      for (int c = 0; c < 4; c++) {
        f16x4 pw;
#pragma unroll
        for (int j = 0; j < 4; j++) pw[j] = (_Float16)(num2[c * 4 + j] * is2);
        *(f16x4*)(&St[i * ROWH + c * 256 + lane * 4]) = pw;
      }
    }
  } else {
#pragma unroll 1
    for (int k = 0; k < 4; k++) {
      const int i = i0 + k;
      float uv[16];
      const unsigned short* ur = up + (size_t)(L + i) * 1024 + lane * 4;
#pragma unroll
      for (int c = 0; c < 4; c++) {
        union { unsigned long long q; unsigned short u[4]; } ld;
        ld.q = *(const unsigned long long*)(ur + c * 256);
#pragma unroll
        for (int j = 0; j < 4; j++) uv[c * 4 + j] = bf2f(ld.u[j]);
      }
      f16x4 sh[4];
#pragma unroll
      for (int c = 0; c < 4; c++)
        sh[c] = *(const f16x4*)(&St[i * ROWH + c * 256 + lane * 4]);
      float num1[16]; float s1 = 0.f;
#pragma unroll
      for (int c = 0; c < 4; c++)
#pragma unroll
        for (int j = 0; j < 4; j++) {
          const float nl = neglog(uv[c * 4 + j] + 1e-10f) + 1e-10f;
          num1[c * 4 + j] = __expf((float)sh[c][j]) * __builtin_amdgcn_rcpf(nl);
          s1 += num1[c * 4 + j];
        }
      s1 = wsum(s1);
      const float is1 = __builtin_amdgcn_rcpf(s1);
      float num2[16]; float s2 = 0.f;
#pragma unroll
      for (int c = 0; c < 4; c++)
#pragma unroll
        for (int j = 0; j < 4; j++) {
          num2[c * 4 + j] = __expf((float)sh[c][j] + num1[c * 4 + j] * is1);
          s2 += num2[c * 4 + j];
        }
      s2 = wsum(s2);
      const float is2 = __builtin_amdgcn_rcpf(s2);
#pragma unroll
      for (int c = 0; c < 4; c++) {
        f16x4 pw;
#pragma unroll
        for (int j = 0; j < 4; j++) pw[j] = (_Float16)(num2[c * 4 + j] * is2);
        *(f16x4*)(&St[i * ROWH + c * 256 + lane * 4]) = pw;
      }
    }
  }
  __syncthreads();

  // ---- Phase C: ctx = P * V via V^T, 4 independent accumulators ----
  f32x4 co[4] = {};
  const _Float16* vrow = vp + (wave * 16 + lm) * 1024;
#pragma unroll
  for (int r0 = 0; r0 < 1024; r0 += 32) {
    const int a = (r0 >> 5) & 3;
    f16x8 pa = *(const f16x8*)(&St[lm * ROWH + r0 + lq * 8]);
    f16x8 vb = *(const f16x8*)(vrow + r0 + lq * 8);
    co[a] = __builtin_amdgcn_mfma_f32_16x16x32_f16(pa, vb, co[a], 0, 0, 0);
  }
  f32x4 cf;
#pragma unroll
  for (int rg = 0; rg < 4; rg++)
    cf[rg] = (co[0][rg] + co[1][rg]) + (co[2][rg] + co[3][rg]);
#pragma unroll
  for (int rg = 0; rg < 4; rg++) {
    const int i = lq * 4 + rg;
    out[(size_t)(b * 1024 + L + i) * 1024 + h * 64 + wave * 16 + lm] = cf[rg];
  }
}

extern "C" void kernel_launch(void* const* d_in, const int* in_sizes, int n_in,
                              void* d_out, int out_size, void* d_ws, size_t ws_size,
                              hipStream_t stream) {
  const unsigned short* hidden = (const unsigned short*)d_in[0];
  const unsigned short* mask   = (const unsigned short*)d_in[1];
  const unsigned short* gum    = (const unsigned short*)d_in[2];
  const unsigned short* Wq     = (const unsigned short*)d_in[3];
  const unsigned short* bq     = (const unsigned short*)d_in[4];
  const unsigned short* Wk     = (const unsigned short*)d_in[5];
  const unsigned short* bk     = (const unsigned short*)d_in[6];
  const unsigned short* Wv     = (const unsigned short*)d_in[7];
  const unsigned short* bv     = (const unsigned short*)d_in[8];
  const unsigned short* de     = (const unsigned short*)d_in[9];

  _Float16* cvt16 = (_Float16*)((char*)d_ws + 256);              // 10 MB (dead after qkv)
  _Float16* q_ws  = cvt16 + (size_t)5 * 1024 * 1024;             // 4 MB
  _Float16* k_ws  = q_ws + (size_t)2 * 1024 * 1024;              // 4 MB
  _Float16* v_ws  = k_ws + (size_t)2 * 1024 * 1024;              // 4 MB
  _Float16* vT_ws = cvt16;             // reuse cvt16 space after qkv consumed it
  float* out = (float*)d_out;

  cvt_inputs<<<dim3(2048, 4), 256, 0, stream>>>(hidden, Wq, Wk, Wv, gum, cvt16);
  qkv_gemm<<<dim3(32, 48), 256, 0, stream>>>(cvt16, bq, bk, bv, gum,
                                             q_ws, k_ws, v_ws);
  transpose_v<<<dim3(16, 32), 256, 0, stream>>>(v_ws, vT_ws);
  attn_kernel<<<2048, 256, 0, stream>>>(q_ws, k_ws, vT_ws, de, gum, mask, out);
}